// Round 1
// 74.065 us; speedup vs baseline: 1.0163x; 1.0163x over previous
//
#include <hip/hip_runtime.h>
#include <math.h>

#define NN   28   // nodes
#define NH   64   // hidden dim
#define WAVES 4   // waves per block (main kernel; no block-wide syncs needed)
#define TPB  (WAVES * 64)
#define EPW  16   // batch elements per wave (MFMA M=16)
#define EPB  (WAVES * EPW)   // 64 elements per block
#define ZSTR 29   // padded LDS stride for transpose buffer

// d_ws layout:
//   [0, 4096)      : packed B-operand frags, short[64 lanes][32]
//                    per lane: bhi0[8] | blo0[8] | bhi1[8] | blo1[8]
//   [4096, 4112)   : float cpos, float cneg, float bias2, int flag
#define WS_CONST_OFF 4096

typedef __attribute__((ext_vector_type(8))) short bf16x8;  // 8 bf16 = 4 VGPR
typedef __attribute__((ext_vector_type(4))) float f32x4;   // MFMA C/D frag

// fp32 -> bf16 round-to-nearest-even (finite inputs)
static __device__ __forceinline__ short f2bf(float f) {
  unsigned u = __float_as_uint(f);
  u = (u + 0x7FFFu + ((u >> 16) & 1u)) >> 16;
  return (short)u;
}
static __device__ __forceinline__ float bf2f(short h) {
  return __uint_as_float(((unsigned)(unsigned short)h) << 16);
}

// ---------------------------------------------------------------------------
// Prelude kernel (1 block): build A_hat once, pre-pack the per-lane split-bf16
// B-operand fragments (layout depends only on lane id) + activation constants
// into d_ws. Removes the per-block atomic prologue from the hot kernel.
// Fragment layout (learn_hip m89/m120 verified):
//   B-op: B[k=(lane>>4)*8+j][n=lane&15], B = A_hat^T  (i.e. reads A[n][k])
// NOTE: harness narrows int64 inputs to int32 -> ei is const int*,
//       src=[0,E), dst=[E,2E).
// ---------------------------------------------------------------------------
__global__ __launch_bounds__(256) void gcn_build(
    const int* __restrict__ ei, int E,
    const float* __restrict__ W1, const float* __restrict__ b1,
    const float* __restrict__ W2, const float* __restrict__ b2,
    void* __restrict__ ws) {
  __shared__ __align__(16) float A[NN * NN];
  __shared__ float dinv[NN];
  __shared__ float cpos_s, cneg_s;
  __shared__ int flag_s;

  const int t = threadIdx.x;

  if (t < NN) dinv[t] = 1.0f;  // self-loop contributes 1 to every degree
  for (int i = t; i < NN * NN; i += 256) A[i] = 0.0f;
  if (t == 0) { cpos_s = 0.0f; cneg_s = 0.0f; flag_s = 0; }
  __syncthreads();

  for (int e = t; e < E; e += 256) atomicAdd(&dinv[ei[E + e]], 1.0f);
  __syncthreads();
  if (t < NN) dinv[t] = 1.0f / sqrtf(dinv[t]);  // deg >= 1 always
  __syncthreads();

  for (int e = t; e < E; e += 256) {
    int s = ei[e];
    int d = ei[E + e];
    atomicAdd(&A[d * NN + s], dinv[s] * dinv[d]);
  }
  if (t < NN) atomicAdd(&A[t * NN + t], dinv[t] * dinv[t]);  // self loops

  // activation constants: f(v) = sum_o relu(W1[o]*v + b1[o]) * W2[o]
  // if b1 == 0: f(v) = v * (v>0 ? cpos : cneg)
  if (t < NH) {
    float w1 = W1[t], w2 = W2[t];
    if (w1 > 0.0f)      atomicAdd(&cpos_s, w1 * w2);
    else if (w1 < 0.0f) atomicAdd(&cneg_s, w1 * w2);
    if (b1[t] != 0.0f) atomicOr(&flag_s, 1);
  }
  __syncthreads();

  // ---- pack per-lane split-bf16 fragments of A^T (B-operand) ----
  if (t < 64) {
    const int q = t >> 4, l15 = t & 15;
    short frag[32];
#pragma unroll
    for (int j = 0; j < 8; ++j) {
      const int k = q * 8 + j;
      const int n1 = 16 + l15;
      float a0 = (k < NN) ? A[l15 * NN + k] : 0.0f;
      float a1 = (n1 < NN && k < NN) ? A[n1 * NN + k] : 0.0f;
      short h0 = f2bf(a0), h1 = f2bf(a1);
      frag[j]      = h0;                    // bhi0
      frag[8 + j]  = f2bf(a0 - bf2f(h0));   // blo0
      frag[16 + j] = h1;                    // bhi1
      frag[24 + j] = f2bf(a1 - bf2f(h1));   // blo1
    }
    short* dstp = (short*)ws + t * 32;
#pragma unroll
    for (int j = 0; j < 32; ++j) dstp[j] = frag[j];
  }
  if (t == 0) {
    float* c = (float*)((char*)ws + WS_CONST_OFF);
    c[0] = cpos_s;
    c[1] = cneg_s;
    c[2] = b2[0];
    ((int*)c)[3] = flag_s;
  }
}

// ---------------------------------------------------------------------------
// Hot kernel: per wave, 16 batch elements via split-bf16 MFMA GEMM:
//   S = X A^T ; Z = f(S) ; O = Z A^T + b2
// No block-wide barriers, no atomics — pure load/MFMA/transpose/store.
// Fragment layouts (learn_hip m89/m120 verified):
//   A-op: A[m=lane&15][k=(lane>>4)*8+j]  (j=0..7)
//   C/D : D[m=(lane>>4)*4+r][n=lane&15]  (r=0..3)
// ---------------------------------------------------------------------------
__global__ __launch_bounds__(TPB) void gcn_main(
    const float* __restrict__ x, const void* __restrict__ ws,
    const float* __restrict__ W1, const float* __restrict__ b1,
    const float* __restrict__ W2,
    float* __restrict__ out, int B) {
  __shared__ float zbuf[WAVES][EPW * ZSTR];  // wave-private transpose buffers

  const int t = threadIdx.x;
  const int wave = t >> 6, lane = t & 63;
  const int q = lane >> 4, l15 = lane & 15;

  // ---- issue x loads first (bulk of the traffic) ----
  const int gelem0 = (blockIdx.x * WAVES + wave) * EPW;  // this wave's 16 elems
  const int me = gelem0 + l15;                           // my A-frag elem (M)
  const bool mv = (me < B);
  const float* xr = x + (size_t)(mv ? me : 0) * NN + q * 8;  // 16B-aligned
  float4 xv0 = *(const float4*)xr;                           // k = q*8..q*8+3
  float4 xv1;                                                // k = q*8+4..+7
  if (q < 3) xv1 = *(const float4*)(xr + 4);
  else       xv1 = make_float4(0.f, 0.f, 0.f, 0.f);          // k=28..31 pad
  if (!mv) { xv0 = make_float4(0.f,0.f,0.f,0.f); xv1 = make_float4(0.f,0.f,0.f,0.f); }

  // ---- pre-packed B-operand frags: 64B/lane, same 4KB for all blocks (L2) ----
  const bf16x8* fp = (const bf16x8*)ws + (size_t)lane * 4;
  const bf16x8 bhi0 = fp[0], blo0 = fp[1], bhi1 = fp[2], blo1 = fp[3];

  // ---- activation constants (uniform scalar loads) ----
  const float* cws = (const float*)((const char*)ws + WS_CONST_OFF);
  const float cpos = cws[0], cneg = cws[1], bias2 = cws[2];
  const int flag = ((const int*)cws)[3];

  // ---- X A-operand frag, split hi/lo ----
  bf16x8 xhi, xlo;
  {
    float xf[8] = {xv0.x, xv0.y, xv0.z, xv0.w, xv1.x, xv1.y, xv1.z, xv1.w};
#pragma unroll
    for (int j = 0; j < 8; ++j) {
      short h = f2bf(xf[j]);
      xhi[j] = h; xlo[j] = f2bf(xf[j] - bf2f(h));
    }
  }

  // ---- Layer 1: S = X A^T (3-product split-bf16) ----
  f32x4 acc0 = {0.f, 0.f, 0.f, 0.f}, acc1 = {0.f, 0.f, 0.f, 0.f};
  acc0 = __builtin_amdgcn_mfma_f32_16x16x32_bf16(xhi, bhi0, acc0, 0, 0, 0);
  acc0 = __builtin_amdgcn_mfma_f32_16x16x32_bf16(xlo, bhi0, acc0, 0, 0, 0);
  acc0 = __builtin_amdgcn_mfma_f32_16x16x32_bf16(xhi, blo0, acc0, 0, 0, 0);
  acc1 = __builtin_amdgcn_mfma_f32_16x16x32_bf16(xhi, bhi1, acc1, 0, 0, 0);
  acc1 = __builtin_amdgcn_mfma_f32_16x16x32_bf16(xlo, bhi1, acc1, 0, 0, 0);
  acc1 = __builtin_amdgcn_mfma_f32_16x16x32_bf16(xhi, blo1, acc1, 0, 0, 0);

  // ---- Activation ----
  float z0[4], z1[4];
  if (flag == 0) {
#pragma unroll
    for (int r = 0; r < 4; ++r) {
      z0[r] = acc0[r] * (acc0[r] > 0.0f ? cpos : cneg);
      z1[r] = acc1[r] * (acc1[r] > 0.0f ? cpos : cneg);
    }
  } else {  // exact fallback (b1 != 0)
#pragma unroll
    for (int r = 0; r < 4; ++r) { z0[r] = 0.0f; z1[r] = 0.0f; }
    for (int o = 0; o < NH; ++o) {
      float w1 = W1[o], bb = b1[o], w2 = W2[o];
#pragma unroll
      for (int r = 0; r < 4; ++r) {
        z0[r] = fmaf(fmaxf(fmaf(acc0[r], w1, bb), 0.0f), w2, z0[r]);
        z1[r] = fmaf(fmaxf(fmaf(acc1[r], w1, bb), 0.0f), w2, z1[r]);
      }
    }
  }

  // ---- C-layout -> A-operand relayout via wave-private LDS ----
  float* zb = zbuf[wave];
#pragma unroll
  for (int r = 0; r < 4; ++r) {
    const int m = q * 4 + r;               // local elem index
    zb[m * ZSTR + l15] = z0[r];            // n = 0..15
    if (l15 < NN - 16) zb[m * ZSTR + 16 + l15] = z1[r];  // n = 16..27
  }
  __builtin_amdgcn_wave_barrier();         // wave-synchronous LDS exchange

  bf16x8 zhi, zlo;
#pragma unroll
  for (int j = 0; j < 8; ++j) {
    const int k = q * 8 + j;
    float v = (k < NN) ? zb[l15 * ZSTR + k] : 0.0f;
    short h = f2bf(v);
    zhi[j] = h; zlo[j] = f2bf(v - bf2f(h));
  }
  __builtin_amdgcn_wave_barrier();

  // ---- Layer 2: O = Z A^T + b2 ----
  f32x4 occ0 = {0.f, 0.f, 0.f, 0.f}, occ1 = {0.f, 0.f, 0.f, 0.f};
  occ0 = __builtin_amdgcn_mfma_f32_16x16x32_bf16(zhi, bhi0, occ0, 0, 0, 0);
  occ0 = __builtin_amdgcn_mfma_f32_16x16x32_bf16(zlo, bhi0, occ0, 0, 0, 0);
  occ0 = __builtin_amdgcn_mfma_f32_16x16x32_bf16(zhi, blo0, occ0, 0, 0, 0);
  occ1 = __builtin_amdgcn_mfma_f32_16x16x32_bf16(zhi, bhi1, occ1, 0, 0, 0);
  occ1 = __builtin_amdgcn_mfma_f32_16x16x32_bf16(zlo, bhi1, occ1, 0, 0, 0);
  occ1 = __builtin_amdgcn_mfma_f32_16x16x32_bf16(zhi, blo1, occ1, 0, 0, 0);

  // ---- stage O in LDS, store coalesced ----
#pragma unroll
  for (int r = 0; r < 4; ++r) {
    const int m = q * 4 + r;
    zb[m * ZSTR + l15] = occ0[r] + bias2;
    if (l15 < NN - 16) zb[m * ZSTR + 16 + l15] = occ1[r] + bias2;
  }
  __builtin_amdgcn_wave_barrier();

  const size_t obase = (size_t)gelem0 * NN;
  const size_t total = (size_t)B * NN;
#pragma unroll
  for (int k7 = 0; k7 < 7; ++k7) {         // 16*28 = 448 = 64 lanes * 7
    const int flat = lane + 64 * k7;
    const unsigned e = (unsigned)flat / NN;  // const div -> magic mul
    const unsigned n = (unsigned)flat - e * NN;
    if (obase + flat < total)
      out[obase + flat] = zb[e * ZSTR + n];  // lane-stride 4B: coalesced
  }
}

extern "C" void kernel_launch(void* const* d_in, const int* in_sizes, int n_in,
                              void* d_out, int out_size, void* d_ws, size_t ws_size,
                              hipStream_t stream) {
  const float* x  = (const float*)d_in[0];
  const int*   ei = (const int*)d_in[1];
  const float* W1 = (const float*)d_in[2];
  const float* b1 = (const float*)d_in[3];
  const float* W2 = (const float*)d_in[4];
  const float* b2 = (const float*)d_in[5];
  float* out = (float*)d_out;

  const int E = in_sizes[1] / 2;   // edge_index is (2, E)
  const int B = in_sizes[0] / NN;  // x is (B, 28)

  // 1) build A_hat + pre-packed lane fragments + activation constants (1 block)
  gcn_build<<<1, 256, 0, stream>>>(ei, E, W1, b1, W2, b2, d_ws);

  // 2) hot kernel: no atomics, no block barriers
  const int blocks = (B + EPB - 1) / EPB;  // 1024 blocks x 256 threads
  gcn_main<<<blocks, TPB, 0, stream>>>(x, d_ws, W1, b1, W2, out, B);
}